// Round 5
// baseline (36.208 us; speedup 1.0000x reference)
//
#include <hip/hip_runtime.h>

// out[b,c,h,w] = x[b,c,h,w] + emb[(h*16)/64, (w*16)/64, c]
//   x:   [16, 384, 64, 64] fp32 (100.7 MB)   emb: [1,16,16,384] fp32 (0.4 MB)
// Cache policy (R3/R4): x CACHED (L3 keeps it resident across replays),
// out NON-TEMPORAL (write-once; don't evict x from L3).
// MLP (R5): each thread does 4 vectors strided by 4 BATCHES
// (1,572,864 vectors = 4 * c*h*w elements), so (c,h,w) -- and hence the
// emb scalar -- is identical for all 4. One emb gather, 4 independent
// x loads in flight, 4 NT stores. 4x per-wave MLP vs R4.

typedef float f32x4 __attribute__((ext_vector_type(4)));

__global__ __launch_bounds__(256) void spatial_emb_add_kernel(
    const f32x4* __restrict__ x,
    const float* __restrict__ emb,
    f32x4* __restrict__ out) {
    const unsigned CHUNK = 1572864u;        // vectors per 4 batches (= nvec/4)
    unsigned v = blockIdx.x * 256u + threadIdx.x;   // v in [0, CHUNK)
    unsigned f = v << 2;                    // flat element index within chunk
    unsigned w0 = f & 63u;                  // w of first lane (mult of 4)
    unsigned h  = (f >> 6) & 63u;           // h
    unsigned c  = (f >> 12) % 384u;         // channel
    float e = emb[(((h >> 2) << 4) + (w0 >> 2)) * 384u + c];

    // 4 independent loads issued back-to-back, then adds, then NT stores.
    f32x4 a0 = x[v];
    f32x4 a1 = x[v + CHUNK];
    f32x4 a2 = x[v + 2u * CHUNK];
    f32x4 a3 = x[v + 3u * CHUNK];
    a0 += e; a1 += e; a2 += e; a3 += e;
    __builtin_nontemporal_store(a0, &out[v]);
    __builtin_nontemporal_store(a1, &out[v + CHUNK]);
    __builtin_nontemporal_store(a2, &out[v + 2u * CHUNK]);
    __builtin_nontemporal_store(a3, &out[v + 3u * CHUNK]);
}

extern "C" void kernel_launch(void* const* d_in, const int* in_sizes, int n_in,
                              void* d_out, int out_size, void* d_ws, size_t ws_size,
                              hipStream_t stream) {
    const f32x4* x   = (const f32x4*)d_in[0];
    const float* emb = (const float*)d_in[1];
    f32x4* out = (f32x4*)d_out;

    const int block = 256;
    const int grid  = 1572864 / block;       // 6144 blocks, 4 vectors/thread
    spatial_emb_add_kernel<<<grid, block, 0, stream>>>(x, emb, out);
}

// Round 6
// 33.296 us; speedup vs baseline: 1.0875x; 1.0875x over previous
//
#include <hip/hip_runtime.h>

// out[b,c,h,w] = x[b,c,h,w] + emb[(h*16)/64, (w*16)/64, c]
//   x:   [16, 384, 64, 64] fp32 (100.7 MB)   emb: [1,16,16,384] fp32 (0.4 MB)
// Cache policy (R3/R4): x CACHED (L3 keeps it resident across replays),
// out NON-TEMPORAL (write-once; don't evict x from L3).
// MLP (R6): 2 vectors per thread from a CONTIGUOUS 512-vector block span
// (v and v+256) -- R5 showed batch-strided streams (25 MB apart) fragment
// DRAM locality and regress. Both loads perfectly coalesced; per-block
// footprint stays one contiguous 8 KB region; 2x in-flight loads/wave.

typedef float f32x4 __attribute__((ext_vector_type(4)));

__device__ __forceinline__ float emb_at(const float* __restrict__ emb, unsigned v) {
    unsigned f = v << 2;                    // flat element index
    unsigned w0 = f & 63u;                  // w of first lane (mult of 4)
    unsigned h  = (f >> 6) & 63u;           // h
    unsigned c  = (f >> 12) % 384u;         // channel
    return emb[(((h >> 2) << 4) + (w0 >> 2)) * 384u + c];
}

__global__ __launch_bounds__(256) void spatial_emb_add_kernel(
    const f32x4* __restrict__ x,
    const float* __restrict__ emb,
    f32x4* __restrict__ out) {
    unsigned v0 = blockIdx.x * 512u + threadIdx.x;  // first vector
    unsigned v1 = v0 + 256u;                        // second, contiguous span

    f32x4 a0 = x[v0];                       // cached: keep x L3-resident
    f32x4 a1 = x[v1];
    float e0 = emb_at(emb, v0);
    float e1 = emb_at(emb, v1);
    a0 += e0;
    a1 += e1;
    __builtin_nontemporal_store(a0, &out[v0]);  // streaming: don't pollute L3
    __builtin_nontemporal_store(a1, &out[v1]);
}

extern "C" void kernel_launch(void* const* d_in, const int* in_sizes, int n_in,
                              void* d_out, int out_size, void* d_ws, size_t ws_size,
                              hipStream_t stream) {
    const f32x4* x   = (const f32x4*)d_in[0];
    const float* emb = (const float*)d_in[1];
    f32x4* out = (f32x4*)d_out;

    const int nvec  = out_size / 4;          // 6,291,456
    const int block = 256;
    const int grid  = nvec / (2 * block);    // 12,288 blocks, 2 vec/thread
    spatial_emb_add_kernel<<<grid, block, 0, stream>>>(x, emb, out);
}